// Round 11
// baseline (118.396 us; speedup 1.0000x reference)
//
#include <hip/hip_runtime.h>
#include <cstdint>
#include <cmath>

#define DD 2048
#define NROW 4096
#define BHALF 2048
#define NT2 32             // K-tiles of 64

typedef __attribute__((ext_vector_type(8))) __bf16 bf16x8;
typedef __attribute__((ext_vector_type(4))) float f32x4;

typedef __attribute__((address_space(1))) const void* as1cv;
typedef __attribute__((address_space(3))) void* as3v;

__device__ __forceinline__ void gload_lds16(const void* g, void* l) {
  __builtin_amdgcn_global_load_lds((as1cv)g, (as3v)l, 16, 0, 0);
}

__device__ __forceinline__ float fixv(float x) {
  if (isnan(x)) return 0.0f;
  if (isinf(x)) return x > 0.0f ? 10000.0f : -10000.0f;
  return x;
}

// ---- workspace layout (bytes) ----
constexpr size_t TB_OFF     = 0;                              // bf16 total [4096][2048]
constexpr size_t SQ_OFF     = (size_t)NROW * DD * 2;          // f32[4096]
constexpr size_t CS_SRC_OFF = SQ_OFF + NROW * 4;              // f32[2048]
constexpr size_t CS_TGT_OFF = CS_SRC_OFF + DD * 4;            // f32[2048]
constexpr size_t ACC_OFF    = CS_TGT_OFF + DD * 4;            // f64[4]
constexpr size_t SCAL_OFF   = ACC_OFF + 4 * 8;                // f32 lin

// Pass 1: nan_to_num, bf16 convert, row sum-of-squares, column sums.
__global__ __launch_bounds__(512) void k_prep(const float* __restrict__ src,
                                              const float* __restrict__ tgt,
                                              __bf16* __restrict__ Tb,
                                              float* __restrict__ sq,
                                              float* __restrict__ cs_src,
                                              float* __restrict__ cs_tgt) {
  int b = blockIdx.x;
  int t = threadIdx.x, l = t & 63, w = t >> 6;
  int half = t >> 8;             // 0: rows 0-7, 1: rows 8-15
  int tc = t & 255;              // col group (8 cols each)
  int row0 = b * 16;
  const float* base = (b < 128) ? (src + (size_t)row0 * DD)
                                : (tgt + (size_t)(row0 - BHALF) * DD);
  float* csp = (b < 128) ? cs_src : cs_tgt;
  int c0 = tc * 8;
  float cacc[8] = {0, 0, 0, 0, 0, 0, 0, 0};
  __shared__ float rbuf[8][8];
  __shared__ float cbuf[256][8];
#pragma unroll
  for (int r = 0; r < 8; ++r) {
    int row = half * 8 + r;
    const float4* p = (const float4*)(base + (size_t)row * DD + c0);
    float4 v0 = p[0], v1 = p[1];
    float x[8] = {v0.x, v0.y, v0.z, v0.w, v1.x, v1.y, v1.z, v1.w};
    bf16x8 bb;
    float a = 0.0f;
#pragma unroll
    for (int j = 0; j < 8; ++j) {
      float f = fixv(x[j]);
      a += f * f;
      cacc[j] += f;
      bb[j] = (__bf16)f;
    }
    *(bf16x8*)(Tb + (size_t)(row0 + row) * DD + c0) = bb;
    for (int o = 32; o; o >>= 1) a += __shfl_xor(a, o);
    if (l == 0) rbuf[w][r] = a;
  }
  if (half == 1) {
#pragma unroll
    for (int j = 0; j < 8; ++j) cbuf[tc][j] = cacc[j];
  }
  __syncthreads();
  if (half == 0) {
#pragma unroll
    for (int j = 0; j < 8; ++j) atomicAdd(&csp[c0 + j], cacc[j] + cbuf[tc][j]);
  }
  if (t < 16) {
    int h = t >> 3, rr = t & 7;
    sq[row0 + h * 8 + rr] = rbuf[h * 4 + 0][rr] + rbuf[h * 4 + 1][rr] +
                            rbuf[h * 4 + 2][rr] + rbuf[h * 4 + 3][rr];
  }
}

// Main: 256x256 tile, 8 waves (2M x 4N, per-wave 128x64), BK=64, 2 buffers.
// 2 phases per K-tile64:
//   P1: 24 ds_reads (aF[8][2], bF[4][2] -- ALL of this tile's LDS reads);
//       lgkm0; BAR_A; 16 MFMA (m0-3 x n0-1 x kk).
//   P2: stage T+2's 8 gload_lds into buf(T&1) [safe: all reads of this buf
//       drained at P1's lgkm0, BAR_A crossed]; vmcnt(8) [retires T+1 exactly];
//       BAR_B [all waves' T+1 landed]; 48 MFMA (rest).
// Ledger: T staged at (T-2):P2; at T:P2 outstanding = T+2's 8 -> vmcnt(8)
// completes T+1, one barrier before its P1 reads. Tail: vmcnt(0) at t=30.
// kk-subtile layout: each 16384-elem kk block is bit-identical to the
// r8-proven buffer layout (same staging lanes, same XOR involution).
__global__ __launch_bounds__(512, 2) void k_mmd(const __bf16* __restrict__ Tb,
                                                const float* __restrict__ sq,
                                                const float* __restrict__ cs_src,
                                                const float* __restrict__ cs_tgt,
                                                double* __restrict__ accd,
                                                float* __restrict__ scal) {
  // XCD-chunked bijective swizzle (256 % 8 == 0)
  int lin = blockIdx.x;
  int t5 = (lin & 7) * 32 + (lin >> 3);
  int bi = t5 >> 4, bj = t5 & 15;

  // LDS: 2 bufs x [2 kk x (A 256x32 + B 256x32)] bf16 = 2 x 64 KiB = 128 KiB
  __shared__ __attribute__((aligned(16))) __bf16 Sb[65536];

  int tid = threadIdx.x, l = tid & 63, w = tid >> 6;
  int wr = w >> 2, wc = w & 3;      // wave -> 128x64 output sub-tile
  int l15 = l & 15;

  f32x4 acc[8][4];
#pragma unroll
  for (int m = 0; m < 8; ++m)
#pragma unroll
    for (int n = 0; n < 4; ++n) acc[m][n] = (f32x4){0.0f, 0.0f, 0.0f, 0.0f};

  // staging (r8-proven): lane l -> row w*16+(l>>2), phys slot l&3,
  // source col pre-swizzled by involution slot^((l>>3)&3)
  int colsw = ((l & 3) ^ ((l >> 3) & 3)) * 8;
  size_t gA0 = (size_t)(bi * 256 + w * 16 + (l >> 2)) * DD + colsw;
  size_t gB0 = (size_t)(bj * 256 + w * 16 + (l >> 2)) * DD + colsw;
  int dW = w * 512;

  // call: stage 128-row half h, kk-subtile kk, K-tile T
#define CALLA(bf, kk, h, T) gload_lds16(                                       \
      Tb + gA0 + (size_t)(h) * 128 * DD + (size_t)(T) * 64 + (kk) * 32,        \
      (void*)(Sb + (bf) + (kk) * 16384 + (h) * 4096 + dW))
#define CALLB(bf, kk, h, T) gload_lds16(                                       \
      Tb + gB0 + (size_t)(h) * 128 * DD + (size_t)(T) * 64 + (kk) * 32,        \
      (void*)(Sb + (bf) + (kk) * 16384 + 8192 + (h) * 4096 + dW))

  // LDS reads (r8-proven swizzle): xk = (slot ^ ((l15>>1)&3))*8
  int xk = (((l >> 4) ^ ((l15 >> 1) & 3))) * 8;
  int aB = (wr * 128 + l15) * 32 + xk;              // + buf + kk*16384 + m*512
  int bB = 8192 + (wc * 64 + l15) * 32 + xk;        // + buf + kk*16384 + n*512

#define BAR()  __builtin_amdgcn_s_barrier()
#define SBAR() __builtin_amdgcn_sched_barrier(0)
#define LGKM0() asm volatile("s_waitcnt lgkmcnt(0)" ::: "memory")

  // ---- prologue: T0 -> buf0, T1 -> buf1; wait T0; barrier ----
#pragma unroll
  for (int kk = 0; kk < 2; ++kk)
#pragma unroll
    for (int h = 0; h < 2; ++h) { CALLA(0, kk, h, 0); CALLB(0, kk, h, 0); }
#pragma unroll
  for (int kk = 0; kk < 2; ++kk)
#pragma unroll
    for (int h = 0; h < 2; ++h) { CALLA(32768, kk, h, 1); CALLB(32768, kk, h, 1); }
  asm volatile("s_waitcnt vmcnt(8)" ::: "memory");
  SBAR(); BAR(); SBAR();

#pragma unroll 1
  for (int t = 0; t < NT2; ++t) {
    const int bf = (t & 1) << 15;   // element offset of this tile's buffer
    // ---------------- P1: ALL 24 ds_reads, then 16 MFMA ----------------
    bf16x8 aF[8][2], bF[4][2];
#pragma unroll
    for (int kk = 0; kk < 2; ++kk) {
#pragma unroll
      for (int m = 0; m < 8; ++m)
        aF[m][kk] = *(const bf16x8*)(Sb + bf + kk * 16384 + aB + m * 512);
#pragma unroll
      for (int n = 0; n < 4; ++n)
        bF[n][kk] = *(const bf16x8*)(Sb + bf + kk * 16384 + bB + n * 512);
    }
    LGKM0(); SBAR();
    BAR(); SBAR();                  // BAR_A: all waves' reads of buf drained
    __builtin_amdgcn_s_setprio(1);
#pragma unroll
    for (int m = 0; m < 4; ++m)
#pragma unroll
      for (int n = 0; n < 2; ++n)
#pragma unroll
        for (int kk = 0; kk < 2; ++kk)
          acc[m][n] = __builtin_amdgcn_mfma_f32_16x16x32_bf16(aF[m][kk], bF[n][kk], acc[m][n], 0, 0, 0);
    __builtin_amdgcn_s_setprio(0);
    SBAR();
    // ---------------- P2: stage T+2 into this buf; counted wait; 48 MFMA ----
    if (t < NT2 - 2) {
#pragma unroll
      for (int kk = 0; kk < 2; ++kk)
#pragma unroll
        for (int h = 0; h < 2; ++h) { CALLA(bf, kk, h, t + 2); CALLB(bf, kk, h, t + 2); }
      asm volatile("s_waitcnt vmcnt(8)" ::: "memory");
    } else if (t == NT2 - 2) {
      asm volatile("s_waitcnt vmcnt(0)" ::: "memory");
    }
    SBAR();
    BAR(); SBAR();                  // BAR_B: all waves' T+1 landed
    __builtin_amdgcn_s_setprio(1);
#pragma unroll
    for (int m = 0; m < 4; ++m)
#pragma unroll
      for (int n = 2; n < 4; ++n)
#pragma unroll
        for (int kk = 0; kk < 2; ++kk)
          acc[m][n] = __builtin_amdgcn_mfma_f32_16x16x32_bf16(aF[m][kk], bF[n][kk], acc[m][n], 0, 0, 0);
#pragma unroll
    for (int m = 4; m < 8; ++m)
#pragma unroll
      for (int n = 0; n < 4; ++n)
#pragma unroll
        for (int kk = 0; kk < 2; ++kk)
          acc[m][n] = __builtin_amdgcn_mfma_f32_16x16x32_bf16(aF[m][kk], bF[n][kk], acc[m][n], 0, 0, 0);
    __builtin_amdgcn_s_setprio(0);
    SBAR();
  }

  // ---- in-block bandwidth (identical deterministic result in every block) ----
  float* red = (float*)Sb;
  float bw;
  {
    float ssq = 0.0f, s2 = 0.0f, dl = 0.0f;
#pragma unroll
    for (int k2 = 0; k2 < 8; ++k2) ssq += sq[tid + k2 * 512];
#pragma unroll
    for (int k2 = 0; k2 < 4; ++k2) {
      int c = tid + k2 * 512;
      float a = cs_src[c], b2 = cs_tgt[c];
      float s = a + b2;
      s2 += s * s;
      float d = (a - b2) * (1.0f / BHALF);
      dl += d * d;
    }
    for (int o = 32; o; o >>= 1) {
      ssq += __shfl_xor(ssq, o);
      s2  += __shfl_xor(s2, o);
      dl  += __shfl_xor(dl, o);
    }
    __syncthreads();               // all K-loop LDS traffic done; reuse Sb
    if (l == 0) { red[w] = ssq; red[8 + w] = s2; red[16 + w] = dl; }
    __syncthreads();
    double S = 0.0, Q = 0.0;
#pragma unroll
    for (int i = 0; i < 8; ++i) { S += red[i]; Q += red[8 + i]; }
    double meanL2 = 2.0 * S / (double)NROW - 2.0 * Q / ((double)NROW * (double)NROW);
    bw = (float)fmax(meanL2, 1e-6);
    if (tid == 0 && lin == 0) {
      double L = 0.0;
      for (int i = 0; i < 8; ++i) L += red[16 + i];
      scal[0] = (float)L;
    }
  }

  // ---- epilogue: L2 -> 5-kernel RBF sum ----
  float inv[5];
#pragma unroll
  for (int i = 0; i < 5; ++i) inv[i] = 1.0f / fmaxf(bw * (float)(1 << i), 1e-6f);

  float sum = 0.0f;
  int rbase = bi * 256 + wr * 128 + ((l >> 4) * 4);
  int cbase = bj * 256 + wc * 64 + l15;
#pragma unroll
  for (int m = 0; m < 8; ++m) {
    float4 sr = *(const float4*)(sq + rbase + m * 16);
    float sqr[4] = {sr.x, sr.y, sr.z, sr.w};
#pragma unroll
    for (int n = 0; n < 4; ++n) {
      float sc = sq[cbase + n * 16];
#pragma unroll
      for (int r = 0; r < 4; ++r) {
        float L2 = sqr[r] + sc - 2.0f * acc[m][n][r];
        L2 = fmaxf(L2, 0.0f);
#pragma unroll
        for (int i = 0; i < 5; ++i) {
          float s = fminf(L2 * inv[i], 50.0f);
          sum += __expf(-s);
        }
      }
    }
  }
  for (int o = 32; o; o >>= 1) sum += __shfl_xor(sum, o);
  if (l == 0) red[32 + w] = sum;
  __syncthreads();
  if (tid == 0) {
    double tot = 0.0;
    for (int i = 0; i < 8; ++i) tot += red[32 + i];
    int cat = (bi >= 8) * 2 + (bj >= 8);
    atomicAdd(accd + cat, tot);
  }
}

__global__ void k_final(const double* __restrict__ accd,
                        const float* __restrict__ scal,
                        float* __restrict__ out) {
  double loss = (accd[0] + accd[3] - accd[1] - accd[2]) * (1.0 / 4194304.0);
  if (!isfinite(loss)) loss = (double)scal[0];
  out[0] = (float)loss;
}

extern "C" void kernel_launch(void* const* d_in, const int* in_sizes, int n_in,
                              void* d_out, int out_size, void* d_ws, size_t ws_size,
                              hipStream_t stream) {
  const float* src = (const float*)d_in[0];
  const float* tgt = (const float*)d_in[1];
  char* ws = (char*)d_ws;
  __bf16* Tb     = (__bf16*)(ws + TB_OFF);
  float*  sq     = (float*)(ws + SQ_OFF);
  float*  cs_src = (float*)(ws + CS_SRC_OFF);
  float*  cs_tgt = (float*)(ws + CS_TGT_OFF);
  double* accd   = (double*)(ws + ACC_OFF);
  float*  scal   = (float*)(ws + SCAL_OFF);

  // zero colsums + category accumulators (ws is NOT re-poisoned between replays)
  hipMemsetAsync(ws + CS_SRC_OFF, 0, (DD * 4) * 2 + 4 * 8, stream);

  k_prep<<<256, 512, 0, stream>>>(src, tgt, Tb, sq, cs_src, cs_tgt);
  k_mmd<<<256, 512, 0, stream>>>(Tb, sq, cs_src, cs_tgt, accd, scal);
  k_final<<<1, 1, 0, stream>>>(accd, scal, (float*)d_out);
}

// Round 12
// 116.874 us; speedup vs baseline: 1.0130x; 1.0130x over previous
//
#include <hip/hip_runtime.h>
#include <cstdint>
#include <cmath>

#define DD 2048
#define NROW 4096
#define BHALF 2048
#define NT2 32             // K-tiles of 64

typedef __attribute__((ext_vector_type(8))) __bf16 bf16x8;
typedef __attribute__((ext_vector_type(4))) float f32x4;

typedef __attribute__((address_space(1))) const void* as1cv;
typedef __attribute__((address_space(3))) void* as3v;

__device__ __forceinline__ void gload_lds16(const void* g, void* l) {
  __builtin_amdgcn_global_load_lds((as1cv)g, (as3v)l, 16, 0, 0);
}

__device__ __forceinline__ float fixv(float x) {
  if (isnan(x)) return 0.0f;
  if (isinf(x)) return x > 0.0f ? 10000.0f : -10000.0f;
  return x;
}

// ---- workspace layout (bytes) ----
constexpr size_t TB_OFF     = 0;                              // bf16 total [4096][2048]
constexpr size_t SQ_OFF     = (size_t)NROW * DD * 2;          // f32[4096]
constexpr size_t CS_SRC_OFF = SQ_OFF + NROW * 4;              // f32[2048]
constexpr size_t CS_TGT_OFF = CS_SRC_OFF + DD * 4;            // f32[2048]
constexpr size_t ACC_OFF    = CS_TGT_OFF + DD * 4;            // f64[4]
constexpr size_t SCAL_OFF   = ACC_OFF + 4 * 8;                // f32 lin

// Pass 1: nan_to_num, bf16 convert, row sum-of-squares, column sums.
__global__ __launch_bounds__(512) void k_prep(const float* __restrict__ src,
                                              const float* __restrict__ tgt,
                                              __bf16* __restrict__ Tb,
                                              float* __restrict__ sq,
                                              float* __restrict__ cs_src,
                                              float* __restrict__ cs_tgt) {
  int b = blockIdx.x;
  int t = threadIdx.x, l = t & 63, w = t >> 6;
  int half = t >> 8;             // 0: rows 0-7, 1: rows 8-15
  int tc = t & 255;              // col group (8 cols each)
  int row0 = b * 16;
  const float* base = (b < 128) ? (src + (size_t)row0 * DD)
                                : (tgt + (size_t)(row0 - BHALF) * DD);
  float* csp = (b < 128) ? cs_src : cs_tgt;
  int c0 = tc * 8;
  float cacc[8] = {0, 0, 0, 0, 0, 0, 0, 0};
  __shared__ float rbuf[8][8];
  __shared__ float cbuf[256][8];
#pragma unroll
  for (int r = 0; r < 8; ++r) {
    int row = half * 8 + r;
    const float4* p = (const float4*)(base + (size_t)row * DD + c0);
    float4 v0 = p[0], v1 = p[1];
    float x[8] = {v0.x, v0.y, v0.z, v0.w, v1.x, v1.y, v1.z, v1.w};
    bf16x8 bb;
    float a = 0.0f;
#pragma unroll
    for (int j = 0; j < 8; ++j) {
      float f = fixv(x[j]);
      a += f * f;
      cacc[j] += f;
      bb[j] = (__bf16)f;
    }
    *(bf16x8*)(Tb + (size_t)(row0 + row) * DD + c0) = bb;
    for (int o = 32; o; o >>= 1) a += __shfl_xor(a, o);
    if (l == 0) rbuf[w][r] = a;
  }
  if (half == 1) {
#pragma unroll
    for (int j = 0; j < 8; ++j) cbuf[tc][j] = cacc[j];
  }
  __syncthreads();
  if (half == 0) {
#pragma unroll
    for (int j = 0; j < 8; ++j) atomicAdd(&csp[c0 + j], cacc[j] + cbuf[tc][j]);
  }
  if (t < 16) {
    int h = t >> 3, rr = t & 7;
    sq[row0 + h * 8 + rr] = rbuf[h * 4 + 0][rr] + rbuf[h * 4 + 1][rr] +
                            rbuf[h * 4 + 2][rr] + rbuf[h * 4 + 3][rr];
  }
}

// Main: 256x256 tile, 8 waves (2M x 4N, per-wave 128x64), BK=64, 2 buffers,
// m201-style 4-phase-per-tile interleave. Phase = {small ds_read batch |
// 1 half-tile stage (2 gload_lds) | SBAR BAR | lgkm0 SBAR | setprio 16 MFMA |
// SBAR BAR}. Quadrants: P1(mh0,nh0) P2(mh0,nh1) P3(mh1,nh1) P4(mh1,nh0).
// Stage schedule (tile U): P1->HA0(U+1) [other buf], P2->HA1(U+1),
// P3->HB0(U+2) [this buf], P4->HB1(U+2) + vmcnt(4).
// WAR: HA(U-1) last read (U-1):P3 (lgkm0-drained) < U:P1 stage; HB(U) last
// read U:P2 < U:P3 stage. RAW: vmcnt(4) at U:P4 retires through HA1(U+1)
// (outstanding then = 12 calls, newest 4 = HB(U+2)); 2 barriers before
// (U+1):P1 reads. Tail: vmcnt(0) at U=NT2-2. Addressing/swizzle = r11-proven.
__global__ __launch_bounds__(512, 2) void k_mmd(const __bf16* __restrict__ Tb,
                                                const float* __restrict__ sq,
                                                const float* __restrict__ cs_src,
                                                const float* __restrict__ cs_tgt,
                                                double* __restrict__ accd,
                                                float* __restrict__ scal) {
  // XCD-chunked bijective swizzle (256 % 8 == 0)
  int lin = blockIdx.x;
  int t5 = (lin & 7) * 32 + (lin >> 3);
  int bi = t5 >> 4, bj = t5 & 15;

  // LDS: 2 bufs x [2 kk x (A 256x32 + B 256x32)] bf16 = 2 x 64 KiB = 128 KiB
  __shared__ __attribute__((aligned(16))) __bf16 Sb[65536];

  int tid = threadIdx.x, l = tid & 63, w = tid >> 6;
  int wr = w >> 2, wc = w & 3;      // wave -> 128x64 output sub-tile
  int l15 = l & 15;

  f32x4 acc[8][4];
#pragma unroll
  for (int m = 0; m < 8; ++m)
#pragma unroll
    for (int n = 0; n < 4; ++n) acc[m][n] = (f32x4){0.0f, 0.0f, 0.0f, 0.0f};

  // staging (r8/r11-proven): lane l -> row w*16+(l>>2), phys slot l&3,
  // source col pre-swizzled by involution slot^((l>>3)&3)
  int colsw = ((l & 3) ^ ((l >> 3) & 3)) * 8;
  size_t gA0 = (size_t)(bi * 256 + w * 16 + (l >> 2)) * DD + colsw;
  size_t gB0 = (size_t)(bj * 256 + w * 16 + (l >> 2)) * DD + colsw;
  int dW = w * 512;

  // stage 128-row(A)/128-col(B) half h, kk-subtile kk, K-tile T (one gload_lds)
#define CALLA(bf, kk, h, T) gload_lds16(                                       \
      Tb + gA0 + (size_t)(h) * 128 * DD + (size_t)(T) * 64 + (kk) * 32,        \
      (void*)(Sb + (bf) + (kk) * 16384 + (h) * 4096 + dW))
#define CALLB(bf, kk, h, T) gload_lds16(                                       \
      Tb + gB0 + (size_t)(h) * 128 * DD + (size_t)(T) * 64 + (kk) * 32,        \
      (void*)(Sb + (bf) + (kk) * 16384 + 8192 + (h) * 4096 + dW))

  // LDS reads (r11-proven swizzle): xk = (slot ^ ((l15>>1)&3))*8
  int xk = (((l >> 4) ^ ((l15 >> 1) & 3))) * 8;
  int aB = (wr * 128 + l15) * 32 + xk;              // + buf + kk*16384 + m*512
  int bB = 8192 + (wc * 64 + l15) * 32 + xk;        // + buf + kk*16384 + n*512

#define BAR()  __builtin_amdgcn_s_barrier()
#define SBAR() __builtin_amdgcn_sched_barrier(0)
#define LGKM0() asm volatile("s_waitcnt lgkmcnt(0)" ::: "memory")

  // ---- prologue: tile0 (8 calls) -> buf0; HB0,HB1(1) (4 calls) -> buf1 ----
#pragma unroll
  for (int kk = 0; kk < 2; ++kk)
#pragma unroll
    for (int h = 0; h < 2; ++h) CALLA(0, kk, h, 0);
#pragma unroll
  for (int kk = 0; kk < 2; ++kk)
#pragma unroll
    for (int h = 0; h < 2; ++h) CALLB(0, kk, h, 0);
#pragma unroll
  for (int kk = 0; kk < 2; ++kk)
#pragma unroll
    for (int h = 0; h < 2; ++h) CALLB(32768, kk, h, 1);
  asm volatile("s_waitcnt vmcnt(4)" ::: "memory");
  SBAR(); BAR(); SBAR();

#pragma unroll 1
  for (int t = 0; t < NT2; ++t) {
    const int bf = (t & 1) << 15;   // buffer of tile t
    const int ob = bf ^ 32768;      // buffer of tile t+1
    bf16x8 aF[4][2], bF[4][2];
    // ========== P1: (mh0,nh0); reads 12; stage HA0(t+1) ==========
#pragma unroll
    for (int kk = 0; kk < 2; ++kk) {
#pragma unroll
      for (int mi = 0; mi < 4; ++mi)
        aF[mi][kk] = *(const bf16x8*)(Sb + bf + kk * 16384 + aB + mi * 512);
#pragma unroll
      for (int n = 0; n < 2; ++n)
        bF[n][kk] = *(const bf16x8*)(Sb + bf + kk * 16384 + bB + n * 512);
    }
    if (t < NT2 - 1) { CALLA(ob, 0, 0, t + 1); CALLA(ob, 1, 0, t + 1); }
    asm volatile("s_waitcnt lgkmcnt(8)" ::: "memory");
    SBAR(); BAR();
    LGKM0(); SBAR();
    __builtin_amdgcn_s_setprio(1);
#pragma unroll
    for (int mi = 0; mi < 4; ++mi)
#pragma unroll
      for (int n = 0; n < 2; ++n)
#pragma unroll
        for (int kk = 0; kk < 2; ++kk)
          acc[mi][n] = __builtin_amdgcn_mfma_f32_16x16x32_bf16(aF[mi][kk], bF[n][kk], acc[mi][n], 0, 0, 0);
    __builtin_amdgcn_s_setprio(0);
    SBAR(); BAR();
    // ========== P2: (mh0,nh1); reads 4; stage HA1(t+1) ==========
#pragma unroll
    for (int kk = 0; kk < 2; ++kk)
#pragma unroll
      for (int n = 2; n < 4; ++n)
        bF[n][kk] = *(const bf16x8*)(Sb + bf + kk * 16384 + bB + n * 512);
    if (t < NT2 - 1) { CALLA(ob, 0, 1, t + 1); CALLA(ob, 1, 1, t + 1); }
    SBAR(); BAR();
    LGKM0(); SBAR();
    __builtin_amdgcn_s_setprio(1);
#pragma unroll
    for (int mi = 0; mi < 4; ++mi)
#pragma unroll
      for (int n = 2; n < 4; ++n)
#pragma unroll
        for (int kk = 0; kk < 2; ++kk)
          acc[mi][n] = __builtin_amdgcn_mfma_f32_16x16x32_bf16(aF[mi][kk], bF[n][kk], acc[mi][n], 0, 0, 0);
    __builtin_amdgcn_s_setprio(0);
    SBAR(); BAR();
    // ========== P3: (mh1,nh1); reads 8 (aF <- mh1); stage HB0(t+2) ==========
#pragma unroll
    for (int kk = 0; kk < 2; ++kk)
#pragma unroll
      for (int mi = 0; mi < 4; ++mi)
        aF[mi][kk] = *(const bf16x8*)(Sb + bf + kk * 16384 + aB + (4 + mi) * 512);
    if (t < NT2 - 2) { CALLB(bf, 0, 0, t + 2); CALLB(bf, 1, 0, t + 2); }
    SBAR(); BAR();
    LGKM0(); SBAR();
    __builtin_amdgcn_s_setprio(1);
#pragma unroll
    for (int mi = 0; mi < 4; ++mi)
#pragma unroll
      for (int n = 2; n < 4; ++n)
#pragma unroll
        for (int kk = 0; kk < 2; ++kk)
          acc[4 + mi][n] = __builtin_amdgcn_mfma_f32_16x16x32_bf16(aF[mi][kk], bF[n][kk], acc[4 + mi][n], 0, 0, 0);
    __builtin_amdgcn_s_setprio(0);
    SBAR(); BAR();
    // ========== P4: (mh1,nh0); no reads; stage HB1(t+2); counted vmcnt ==========
    if (t < NT2 - 2) {
      CALLB(bf, 0, 1, t + 2); CALLB(bf, 1, 1, t + 2);
      asm volatile("s_waitcnt vmcnt(4)" ::: "memory");
    } else if (t == NT2 - 2) {
      asm volatile("s_waitcnt vmcnt(0)" ::: "memory");
    }
    SBAR(); BAR(); SBAR();
    __builtin_amdgcn_s_setprio(1);
#pragma unroll
    for (int mi = 0; mi < 4; ++mi)
#pragma unroll
      for (int n = 0; n < 2; ++n)
#pragma unroll
        for (int kk = 0; kk < 2; ++kk)
          acc[4 + mi][n] = __builtin_amdgcn_mfma_f32_16x16x32_bf16(aF[mi][kk], bF[n][kk], acc[4 + mi][n], 0, 0, 0);
    __builtin_amdgcn_s_setprio(0);
    SBAR(); BAR();
  }

  // ---- in-block bandwidth (identical deterministic result in every block) ----
  float* red = (float*)Sb;
  float bw;
  {
    float ssq = 0.0f, s2 = 0.0f, dl = 0.0f;
#pragma unroll
    for (int k2 = 0; k2 < 8; ++k2) ssq += sq[tid + k2 * 512];
#pragma unroll
    for (int k2 = 0; k2 < 4; ++k2) {
      int c = tid + k2 * 512;
      float a = cs_src[c], b2 = cs_tgt[c];
      float s = a + b2;
      s2 += s * s;
      float d = (a - b2) * (1.0f / BHALF);
      dl += d * d;
    }
    for (int o = 32; o; o >>= 1) {
      ssq += __shfl_xor(ssq, o);
      s2  += __shfl_xor(s2, o);
      dl  += __shfl_xor(dl, o);
    }
    __syncthreads();               // all K-loop LDS traffic done; reuse Sb
    if (l == 0) { red[w] = ssq; red[8 + w] = s2; red[16 + w] = dl; }
    __syncthreads();
    double S = 0.0, Q = 0.0;
#pragma unroll
    for (int i = 0; i < 8; ++i) { S += red[i]; Q += red[8 + i]; }
    double meanL2 = 2.0 * S / (double)NROW - 2.0 * Q / ((double)NROW * (double)NROW);
    bw = (float)fmax(meanL2, 1e-6);
    if (tid == 0 && lin == 0) {
      double L = 0.0;
      for (int i = 0; i < 8; ++i) L += red[16 + i];
      scal[0] = (float)L;
    }
  }

  // ---- epilogue: L2 -> 5-kernel RBF sum ----
  float inv[5];
#pragma unroll
  for (int i = 0; i < 5; ++i) inv[i] = 1.0f / fmaxf(bw * (float)(1 << i), 1e-6f);

  float sum = 0.0f;
  int rbase = bi * 256 + wr * 128 + ((l >> 4) * 4);
  int cbase = bj * 256 + wc * 64 + l15;
#pragma unroll
  for (int m = 0; m < 8; ++m) {
    float4 sr = *(const float4*)(sq + rbase + m * 16);
    float sqr[4] = {sr.x, sr.y, sr.z, sr.w};
#pragma unroll
    for (int n = 0; n < 4; ++n) {
      float sc = sq[cbase + n * 16];
#pragma unroll
      for (int r = 0; r < 4; ++r) {
        float L2 = sqr[r] + sc - 2.0f * acc[m][n][r];
        L2 = fmaxf(L2, 0.0f);
#pragma unroll
        for (int i = 0; i < 5; ++i) {
          float s = fminf(L2 * inv[i], 50.0f);
          sum += __expf(-s);
        }
      }
    }
  }
  for (int o = 32; o; o >>= 1) sum += __shfl_xor(sum, o);
  if (l == 0) red[32 + w] = sum;
  __syncthreads();
  if (tid == 0) {
    double tot = 0.0;
    for (int i = 0; i < 8; ++i) tot += red[32 + i];
    int cat = (bi >= 8) * 2 + (bj >= 8);
    atomicAdd(accd + cat, tot);
  }
}

__global__ void k_final(const double* __restrict__ accd,
                        const float* __restrict__ scal,
                        float* __restrict__ out) {
  double loss = (accd[0] + accd[3] - accd[1] - accd[2]) * (1.0 / 4194304.0);
  if (!isfinite(loss)) loss = (double)scal[0];
  out[0] = (float)loss;
}

extern "C" void kernel_launch(void* const* d_in, const int* in_sizes, int n_in,
                              void* d_out, int out_size, void* d_ws, size_t ws_size,
                              hipStream_t stream) {
  const float* src = (const float*)d_in[0];
  const float* tgt = (const float*)d_in[1];
  char* ws = (char*)d_ws;
  __bf16* Tb     = (__bf16*)(ws + TB_OFF);
  float*  sq     = (float*)(ws + SQ_OFF);
  float*  cs_src = (float*)(ws + CS_SRC_OFF);
  float*  cs_tgt = (float*)(ws + CS_TGT_OFF);
  double* accd   = (double*)(ws + ACC_OFF);
  float*  scal   = (float*)(ws + SCAL_OFF);

  // zero colsums + category accumulators (ws is NOT re-poisoned between replays)
  hipMemsetAsync(ws + CS_SRC_OFF, 0, (DD * 4) * 2 + 4 * 8, stream);

  k_prep<<<256, 512, 0, stream>>>(src, tgt, Tb, sq, cs_src, cs_tgt);
  k_mmd<<<256, 512, 0, stream>>>(Tb, sq, cs_src, cs_tgt, accd, scal);
  k_final<<<1, 1, 0, stream>>>(accd, scal, (float*)d_out);
}